// Round 2
// baseline (53.533 us; speedup 1.0000x reference)
//
#include <hip/hip_runtime.h>
#include <math.h>

#define DIM 512
#define NROWS 50000
#define NORM 0.04419417382415922f   // 1/sqrt(512)

#define QPART_BLOCKS 32             // 16 rows of W_query each
#define VK_BLOCKS 128               // 4 rows of W_key each (wave-per-row)
#define CP_BLOCKS 1024
#define CP_THREADS 256

// out layout (floats): [0,512) q_max | [512] attn_max | [513] log_attn_max
//                      | [514,1026) concat | [1026,51026) maskf | [51026] max_indx
#define OUT_ATTN 512
#define OUT_LOG  513
#define OUT_IDX  51026

// ws layout (floats):
// [0,16384) qpart (32x512) | [16384,16896) v | [16896,17920) pm
// [17920,18944) ps | [18944,19968) pidx(int) | [19968] counter(uint)

__device__ inline float dot4(float4 a, float4 b, float acc) {
    acc = fmaf(a.x, b.x, acc);
    acc = fmaf(a.y, b.y, acc);
    acc = fmaf(a.z, b.z, acc);
    acc = fmaf(a.w, b.w, acc);
    return acc;
}

// online-softmax + first-occurrence argmax combine (associative)
__device__ inline void sm_combine(float& m, float& s, int& idx,
                                  float m2, float s2, int idx2) {
    bool take2 = (m2 > m) || (m2 == m && idx2 < idx);
    float hm = take2 ? m2 : m;
    float hs = take2 ? s2 : s;
    int   hi = take2 ? idx2 : idx;
    float lm = take2 ? m : m2;
    float ls = take2 ? s : s2;
    if (lm > -INFINITY) hs = fmaf(ls, expf(lm - hm), hs);
    m = hm; s = hs; idx = hi;
}

// Stage 1: concat, g_context, split-K partials of Q = g_context @ W_query.
// Also zeroes the last-block counter used by stage 3.
__global__ __launch_bounds__(256) void qpart_kernel(
    const float* __restrict__ l, const float* __restrict__ ctx,
    const float* __restrict__ g, const float* __restrict__ Wc,
    const float* __restrict__ Wg, const float* __restrict__ Wq,
    float* __restrict__ qpart, float* __restrict__ out_concat,
    unsigned* __restrict__ counter) {
    __shared__ float gctx[DIM];
    int t = threadIdx.x;
    if (blockIdx.x == 0 && t == 0) *counter = 0u;
    float wc0 = Wc[0], wc1 = Wc[1], wg0 = Wg[0], wg1 = Wg[1];
    for (int j = t; j < DIM; j += 256) {
        float cc = wc0 * l[j] + wc1 * ctx[j];
        if (blockIdx.x == 0) out_concat[j] = cc;
        gctx[j] = wg0 * g[j] + wg1 * cc;
    }
    __syncthreads();
    int d0 = blockIdx.x * 16;
    float acc0 = 0.f, acc1 = 0.f;
    for (int d = d0; d < d0 + 16; ++d) {
        float gd = gctx[d];
        acc0 = fmaf(gd, Wq[d * DIM + t], acc0);
        acc1 = fmaf(gd, Wq[d * DIM + t + 256], acc1);
    }
    qpart[blockIdx.x * DIM + t] = acc0;
    qpart[blockIdx.x * DIM + t + 256] = acc1;
}

// Stage 2: reduce Q partials (fixed order) then v[r] = W_key[r,:] . Q
__global__ __launch_bounds__(256) void v_kernel(
    const float* __restrict__ Wk, const float* __restrict__ qpart,
    float* __restrict__ v) {
    __shared__ __align__(16) float Q[DIM];
    int t = threadIdx.x;
    for (int j = t; j < DIM; j += 256) {
        float a = 0.f;
        for (int p = 0; p < QPART_BLOCKS; ++p) a += qpart[p * DIM + j];
        Q[j] = a;
    }
    __syncthreads();
    int lane = t & 63;
    int w = t >> 6;
    int r = blockIdx.x * 4 + w;
    const float4* row = (const float4*)(Wk + (size_t)r * DIM);
    const float4* qv = (const float4*)Q;
    float4 a0 = row[lane],      a1 = row[lane + 64];
    float4 b0 = qv[lane],       b1 = qv[lane + 64];
    float d = dot4(a1, b1, dot4(a0, b0, 0.f));
    #pragma unroll
    for (int off = 32; off > 0; off >>= 1) d += __shfl_xor(d, off);
    if (lane == 0) v[r] = d;
}

// Stage 3: per-wave dots (2 rows in flight), online-softmax partials,
// mask->float output, and last-block finalize (no compat array stored).
__global__ __launch_bounds__(CP_THREADS) void compat_kernel(
    const float* __restrict__ q, const int* __restrict__ mask,
    const float* __restrict__ v,
    float* __restrict__ pm, float* __restrict__ ps, int* __restrict__ pidx,
    unsigned* __restrict__ counter, const int* __restrict__ is_random,
    const long long* __restrict__ rnet, float* __restrict__ out) {
    int t = threadIdx.x;
    int gtid = blockIdx.x * CP_THREADS + t;
    int gsz = CP_BLOCKS * CP_THREADS;
    float* out_maskf = out + 1026;
    for (int i = gtid; i < NROWS; i += gsz)
        out_maskf[i] = (float)mask[i];

    int lane = t & 63;
    int wid = gtid >> 6;
    int nw = gsz >> 6;               // 4096 waves

    const float4* vv = (const float4*)v;
    float4 b0 = vv[lane];
    float4 b1 = vv[lane + 64];

    float m = -INFINITY, s = 0.f;
    int idx = 0x7fffffff;

    // software-pipelined masks; two rows' loads in flight per iteration
    int n = wid;
    int mk1 = (n < NROWS) ? mask[n] : 0;
    int mk2 = (n + nw < NROWS) ? mask[n + nw] : 0;
    for (; n < NROWS; n += 2 * nw) {
        int nn = n + 2 * nw;
        int mk1n = (nn < NROWS) ? mask[nn] : 0;
        int mk2n = (nn + nw < NROWS) ? mask[nn + nw] : 0;

        float4 a0, a1, c0, c1;
        if (mk1) {
            const float4* r1 = (const float4*)(q + (size_t)n * DIM);
            a0 = r1[lane]; a1 = r1[lane + 64];
        }
        if (mk2) {
            const float4* r2 = (const float4*)(q + (size_t)(n + nw) * DIM);
            c0 = r2[lane]; c1 = r2[lane + 64];
        }
        float d1 = 0.f, d2 = 0.f;
        if (mk1) d1 = dot4(a1, b1, dot4(a0, b0, 0.f));
        if (mk2) d2 = dot4(c1, b1, dot4(c0, b0, 0.f));
        #pragma unroll
        for (int off = 32; off > 0; off >>= 1) {
            d1 += __shfl_xor(d1, off);
            d2 += __shfl_xor(d2, off);
        }
        if (mk1) sm_combine(m, s, idx, tanhf(NORM * d1) * 10.0f, 1.0f, n);
        if (mk2) sm_combine(m, s, idx, tanhf(NORM * d2) * 10.0f, 1.0f, n + nw);
        mk1 = mk1n; mk2 = mk2n;
    }

    __shared__ float bm[CP_THREADS / 64], bs[CP_THREADS / 64];
    __shared__ int bidx[CP_THREADS / 64];
    int w = t >> 6;
    if (lane == 0) { bm[w] = m; bs[w] = s; bidx[w] = idx; }
    __syncthreads();

    __shared__ int lastFlag;
    if (t == 0) {
        float M = bm[0], S = bs[0];
        int I = bidx[0];
        for (int i = 1; i < CP_THREADS / 64; ++i)
            sm_combine(M, S, I, bm[i], bs[i], bidx[i]);
        pm[blockIdx.x] = M;
        ps[blockIdx.x] = S;
        pidx[blockIdx.x] = I;
        __threadfence();
        unsigned old = atomicAdd(counter, 1u);
        lastFlag = (old == CP_BLOCKS - 1) ? 1 : 0;
    }
    __syncthreads();
    if (!lastFlag) return;
    __threadfence();   // acquire: partials from all blocks now visible

    // ---- finalize (one block, 256 threads) ----
    __shared__ float fm[CP_THREADS], fs[CP_THREADS];
    __shared__ int fi[CP_THREADS];
    float M = -INFINITY, S = 0.f;
    int I = 0x7fffffff;
    for (int i = t; i < CP_BLOCKS; i += CP_THREADS)
        sm_combine(M, S, I, pm[i], ps[i], pidx[i]);
    fm[t] = M; fs[t] = S; fi[t] = I;
    __syncthreads();
    for (int off = CP_THREADS / 2; off > 0; off >>= 1) {
        if (t < off) {
            float M2 = fm[t], S2 = fs[t];
            int I2 = fi[t];
            sm_combine(M2, S2, I2, fm[t + off], fs[t + off], fi[t + off]);
            fm[t] = M2; fs[t] = S2; fi[t] = I2;
        }
        __syncthreads();
    }
    __shared__ int chosenIx, chosenRnd;
    __shared__ float chosenM, chosenS;
    if (t == 0) {
        chosenRnd = is_random[0];
        chosenIx = chosenRnd ? (int)rnet[0] : fi[0];
        chosenM = fm[0];
        chosenS = fs[0];
    }
    __syncthreads();
    int ix = chosenIx;
    float rv0 = q[(size_t)ix * DIM + t];
    float rv1 = q[(size_t)ix * DIM + t + 256];
    out[t] = rv0;
    out[t + 256] = rv1;
    fm[t] = fmaf(rv0, v[t], rv1 * v[t + 256]);
    __syncthreads();
    for (int off = CP_THREADS / 2; off > 0; off >>= 1) {
        if (t < off) fm[t] += fm[t + off];
        __syncthreads();
    }
    if (t == 0) {
        float Mv = chosenM, Sv = chosenS;
        float c;
        if (chosenRnd)
            c = mask[ix] ? tanhf(NORM * fm[0]) * 10.0f : -INFINITY;
        else
            c = Mv;                          // argmax row: compat == M exactly
        out[OUT_ATTN] = expf(c - Mv) / Sv;
        out[OUT_LOG]  = (c - Mv) - logf(Sv);
        out[OUT_IDX]  = (float)ix;
    }
}

extern "C" void kernel_launch(void* const* d_in, const int* in_sizes, int n_in,
                              void* d_out, int out_size, void* d_ws, size_t ws_size,
                              hipStream_t stream) {
    const float*     q    = (const float*)d_in[0];
    const float*     l    = (const float*)d_in[1];
    const float*     ctx  = (const float*)d_in[2];
    const float*     g    = (const float*)d_in[3];
    const int*       mask = (const int*)d_in[4];
    const int*       isr  = (const int*)d_in[5];
    const long long* rnet = (const long long*)d_in[6];
    const float*     Wc   = (const float*)d_in[7];
    const float*     Wg   = (const float*)d_in[8];
    const float*     Wq   = (const float*)d_in[9];
    const float*     Wk   = (const float*)d_in[10];

    float* out = (float*)d_out;
    float* ws  = (float*)d_ws;
    float*    qpart   = ws;
    float*    v       = ws + 16384;
    float*    pm      = ws + 16896;
    float*    ps      = ws + 17920;
    int*      pidx    = (int*)(ws + 18944);
    unsigned* counter = (unsigned*)(ws + 19968);

    qpart_kernel<<<QPART_BLOCKS, 256, 0, stream>>>(l, ctx, g, Wc, Wg, Wq, qpart, out + 514, counter);
    v_kernel<<<VK_BLOCKS, 256, 0, stream>>>(Wk, qpart, v);
    compat_kernel<<<CP_BLOCKS, CP_THREADS, 0, stream>>>(q, mask, v, pm, ps, pidx, counter, isr, rnet, out);
}

// Round 3
// 29.893 us; speedup vs baseline: 1.7908x; 1.7908x over previous
//
#include <hip/hip_runtime.h>
#include <math.h>

#define DIM 512
#define NROWS 50000
#define NORM 0.04419417382415922f   // 1/sqrt(512)

#define QP_BLOCKS 64                // 32 compute qpart; all 64 copy maskf
#define QPART_BLOCKS 32             // 16 rows of W_query each
#define VK_BLOCKS 128               // 4 rows of W_key each (wave-per-row)
#define CP_BLOCKS 2048              // fills 256 CU x 32 waves
#define CP_THREADS 256

// out layout (floats): [0,512) q_max | [512] attn_max | [513] log_attn_max
//                      | [514,1026) concat | [1026,51026) maskf | [51026] max_indx
#define OUT_ATTN 512
#define OUT_LOG  513
#define OUT_IDX  51026

// ws layout (floats):
// [0,16384) qpart (32x512) | [16384,16896) v | [16896,18944) pm
// [18944,20992) ps | [20992,23040) pidx(int) | [23040,73040) compat

__device__ inline float dot4(float4 a, float4 b, float acc) {
    acc = fmaf(a.x, b.x, acc);
    acc = fmaf(a.y, b.y, acc);
    acc = fmaf(a.z, b.z, acc);
    acc = fmaf(a.w, b.w, acc);
    return acc;
}

// online-softmax + first-occurrence argmax combine (associative)
__device__ inline void sm_combine(float& m, float& s, int& idx,
                                  float m2, float s2, int idx2) {
    bool take2 = (m2 > m) || (m2 == m && idx2 < idx);
    float hm = take2 ? m2 : m;
    float hs = take2 ? s2 : s;
    int   hi = take2 ? idx2 : idx;
    float lm = take2 ? m : m2;
    float ls = take2 ? s : s2;
    if (lm > -INFINITY) hs = fmaf(ls, expf(lm - hm), hs);
    m = hm; s = hs; idx = hi;
}

// Stage 1: concat, g_context, split-K partials of Q = g_context @ W_query.
// Extra blocks handle the mask -> float copy so compat stays pure.
__global__ __launch_bounds__(256) void qpart_kernel(
    const float* __restrict__ l, const float* __restrict__ ctx,
    const float* __restrict__ g, const float* __restrict__ Wc,
    const float* __restrict__ Wg, const float* __restrict__ Wq,
    const int* __restrict__ mask,
    float* __restrict__ qpart, float* __restrict__ out_concat,
    float* __restrict__ out_maskf) {
    int t = threadIdx.x;
    int b = blockIdx.x;
    for (int i = b * 256 + t; i < NROWS; i += QP_BLOCKS * 256)
        out_maskf[i] = (float)mask[i];
    if (b >= QPART_BLOCKS) return;

    __shared__ float gctx[DIM];
    float wc0 = Wc[0], wc1 = Wc[1], wg0 = Wg[0], wg1 = Wg[1];
    for (int j = t; j < DIM; j += 256) {
        float cc = wc0 * l[j] + wc1 * ctx[j];
        if (b == 0) out_concat[j] = cc;
        gctx[j] = wg0 * g[j] + wg1 * cc;
    }
    __syncthreads();
    int d0 = b * 16;
    float acc0 = 0.f, acc1 = 0.f;
    for (int d = d0; d < d0 + 16; ++d) {
        float gd = gctx[d];
        acc0 = fmaf(gd, Wq[d * DIM + t], acc0);
        acc1 = fmaf(gd, Wq[d * DIM + t + 256], acc1);
    }
    qpart[b * DIM + t] = acc0;
    qpart[b * DIM + t + 256] = acc1;
}

// Stage 2: reduce Q partials (fixed order) then v[r] = W_key[r,:] . Q
__global__ __launch_bounds__(256) void v_kernel(
    const float* __restrict__ Wk, const float* __restrict__ qpart,
    float* __restrict__ v) {
    __shared__ __align__(16) float Q[DIM];
    int t = threadIdx.x;
    for (int j = t; j < DIM; j += 256) {
        float a = 0.f;
        for (int p = 0; p < QPART_BLOCKS; ++p) a += qpart[p * DIM + j];
        Q[j] = a;
    }
    __syncthreads();
    int lane = t & 63;
    int w = t >> 6;
    int r = blockIdx.x * 4 + w;
    const float4* row = (const float4*)(Wk + (size_t)r * DIM);
    const float4* qv = (const float4*)Q;
    float4 a0 = row[lane],      a1 = row[lane + 64];
    float4 b0 = qv[lane],       b1 = qv[lane + 64];
    float d = dot4(a1, b1, dot4(a0, b0, 0.f));
    #pragma unroll
    for (int off = 32; off > 0; off >>= 1) d += __shfl_xor(d, off);
    if (lane == 0) v[r] = d;
}

// Stage 3: compat[n] = tanh(norm * q[n].v)*10 (masked -> -inf, row skipped),
// per-block online-softmax partial. Round-1 proven structure, 2x the waves.
__global__ __launch_bounds__(CP_THREADS) void compat_kernel(
    const float* __restrict__ q, const int* __restrict__ mask,
    const float* __restrict__ v, float* __restrict__ compat,
    float* __restrict__ pm, float* __restrict__ ps, int* __restrict__ pidx) {
    int t = threadIdx.x;
    int gtid = blockIdx.x * CP_THREADS + t;
    int gsz = CP_BLOCKS * CP_THREADS;

    int lane = t & 63;
    int wid = gtid >> 6;
    int nw = gsz >> 6;               // 8192 waves

    const float4* vv = (const float4*)v;
    float4 b0 = vv[lane];
    float4 b1 = vv[lane + 64];

    float m = -INFINITY, s = 0.f;
    int idx = 0x7fffffff;

    for (int n = wid; n < NROWS; n += nw) {
        if (mask[n] == 0) {               // wave-uniform branch
            if (lane == 0) compat[n] = -INFINITY;
            continue;                      // skip the 2KB row read entirely
        }
        const float4* row = (const float4*)(q + (size_t)n * DIM);
        float4 a0 = row[lane];
        float4 a1 = row[lane + 64];
        float d = dot4(a1, b1, dot4(a0, b0, 0.f));
        #pragma unroll
        for (int off = 32; off > 0; off >>= 1) d += __shfl_xor(d, off);
        float c = tanhf(NORM * d) * 10.0f;
        if (lane == 0) compat[n] = c;
        sm_combine(m, s, idx, c, 1.0f, n);
    }

    __shared__ float bm[CP_THREADS / 64], bs[CP_THREADS / 64];
    __shared__ int bidx[CP_THREADS / 64];
    int w = t >> 6;
    if (lane == 0) { bm[w] = m; bs[w] = s; bidx[w] = idx; }
    __syncthreads();
    if (t == 0) {
        float M = bm[0], S = bs[0];
        int I = bidx[0];
        for (int i = 1; i < CP_THREADS / 64; ++i)
            sm_combine(M, S, I, bm[i], bs[i], bidx[i]);
        pm[blockIdx.x] = M;
        ps[blockIdx.x] = S;
        pidx[blockIdx.x] = I;
    }
}

// Stage 4: combine partials, write attn/log_attn/idx, copy q[idx].
__global__ __launch_bounds__(512) void finalize_kernel(
    const float* __restrict__ q, const float* __restrict__ pm,
    const float* __restrict__ ps, const int* __restrict__ pidx,
    const float* __restrict__ compat, const int* __restrict__ is_random,
    const long long* __restrict__ rnet, float* __restrict__ out) {
    __shared__ float sm[512], ss[512];
    __shared__ int si[512];
    __shared__ int chosen;
    int t = threadIdx.x;
    float m = -INFINITY, s = 0.f;
    int idx = 0x7fffffff;
    for (int i = t; i < CP_BLOCKS; i += 512)
        sm_combine(m, s, idx, pm[i], ps[i], pidx[i]);
    sm[t] = m; ss[t] = s; si[t] = idx;
    __syncthreads();
    for (int off = 256; off > 0; off >>= 1) {
        if (t < off) {
            float M = sm[t], S = ss[t];
            int I = si[t];
            sm_combine(M, S, I, sm[t + off], ss[t + off], si[t + off]);
            sm[t] = M; ss[t] = S; si[t] = I;
        }
        __syncthreads();
    }
    if (t == 0) {
        float M = sm[0], S = ss[0];
        int ix = si[0];
        if (is_random[0] != 0) ix = (int)rnet[0];
        float c = compat[ix];
        out[OUT_ATTN] = expf(c - M) / S;
        out[OUT_LOG]  = (c - M) - logf(S);
        out[OUT_IDX]  = (float)ix;
        chosen = ix;
    }
    __syncthreads();
    out[t] = q[(size_t)chosen * DIM + t];
}

extern "C" void kernel_launch(void* const* d_in, const int* in_sizes, int n_in,
                              void* d_out, int out_size, void* d_ws, size_t ws_size,
                              hipStream_t stream) {
    const float*     q    = (const float*)d_in[0];
    const float*     l    = (const float*)d_in[1];
    const float*     ctx  = (const float*)d_in[2];
    const float*     g    = (const float*)d_in[3];
    const int*       mask = (const int*)d_in[4];
    const int*       isr  = (const int*)d_in[5];
    const long long* rnet = (const long long*)d_in[6];
    const float*     Wc   = (const float*)d_in[7];
    const float*     Wg   = (const float*)d_in[8];
    const float*     Wq   = (const float*)d_in[9];
    const float*     Wk   = (const float*)d_in[10];

    float* out = (float*)d_out;
    float* ws  = (float*)d_ws;
    float* qpart  = ws;
    float* v      = ws + 16384;
    float* pm     = ws + 16896;
    float* ps     = ws + 18944;
    int*   pidx   = (int*)(ws + 20992);
    float* compat = ws + 23040;

    qpart_kernel<<<QP_BLOCKS, 256, 0, stream>>>(l, ctx, g, Wc, Wg, Wq, mask, qpart, out + 514, out + 1026);
    v_kernel<<<VK_BLOCKS, 256, 0, stream>>>(Wk, qpart, v);
    compat_kernel<<<CP_BLOCKS, CP_THREADS, 0, stream>>>(q, mask, v, compat, pm, ps, pidx);
    finalize_kernel<<<1, 512, 0, stream>>>(q, pm, ps, pidx, compat, isr, rnet, out);
}